// Round 1
// baseline (785.951 us; speedup 1.0000x reference)
//
#include <hip/hip_runtime.h>
#include <stdint.h>

#define B_SZ 8192
#define H_SZ 512

typedef short bfrag8 __attribute__((ext_vector_type(8)));
typedef float f32x4 __attribute__((ext_vector_type(4)));

__device__ __forceinline__ unsigned short f2bf(float f) {
  union { float f; uint32_t u; } c; c.f = f;
  uint32_t u = c.u;
  uint32_t r = (u + 0x7FFFu + ((u >> 16) & 1u)) >> 16;
  return (unsigned short)r;
}
__device__ __forceinline__ float bf2f(unsigned short u) {
  union { uint32_t u; float f; } c; c.u = ((uint32_t)u) << 16;
  return c.f;
}
__device__ __forceinline__ float sigm(float x) { return 1.0f / (1.0f + __expf(-x)); }
__device__ __forceinline__ float tanh_fast(float x) {
  float cx = fminf(fmaxf(x, -15.0f), 15.0f);
  float e = __expf(2.0f * cx);
  return (e - 1.0f) / (e + 1.0f);
}

__device__ __forceinline__ void gload16(const void* g, void* l) {
  __builtin_amdgcn_global_load_lds(
      (const __attribute__((address_space(1))) void*)g,
      (__attribute__((address_space(3))) void*)l, 16, 0, 0);
}

struct GemmArgs {
  const unsigned short* Ah[3];
  const unsigned short* Ac[3];
  const unsigned short* Bh;
  const unsigned short* Bc;
  int ldA, ldB;
  const float* biash;
  const float* biasc;
  unsigned short* outBf;
  float* outF;
  // gates mode
  const float* pc;
  const float* x;
  const float* W_ih;
  const float* b_ih;
  const float* b_hh;
  int cell, last;
  float* gh_out; float* gc_out;
  unsigned short* ring_h; unsigned short* ring_c;
  const float* h_ext; const float* c_ext;
  float* fh_out; float* fc_out;
  unsigned short* finalBf;
};

// MODE 0: ph/pc GEMM (z=0 -> ph bf16 out, z=1 -> pc f32 out), up to 3 K-segments of 512
// MODE 1: gates GEMM [8192x512]@[512x2048 remapped] + fused LSTM state update epilogue
// MODE 2: FC1 GEMM [8192x1024]@[1024x256] + bias + relu -> bf16
template <int MODE>
__global__ __launch_bounds__(256, 2)
void gemm_k(GemmArgs g) {
  __shared__ __align__(16) char As[16384];  // 128 rows x 64 bf16 (128 B/row)
  __shared__ __align__(16) char Bs[16384];
  const int tid = threadIdx.x;
  const int lane = tid & 63;
  const int wv = tid >> 6;
  const int wr = wv >> 1, wc = wv & 1;
  const int m0 = blockIdx.y * 128;
  const int z = (MODE == 0) ? blockIdx.z : 0;

  const unsigned short* const* Aseg = (MODE == 0 && z == 1) ? g.Ac : g.Ah;
  const unsigned short* Bb = (MODE == 0 && z == 1) ? g.Bc : g.Bh;

  // per-thread staging geometry (4 chunks of 16B each for A and B tiles)
  int rowA[4], cgA[4];
  const char* browPtr[4];
#pragma unroll
  for (int q = 0; q < 4; ++q) {
    int cl = q * 256 + tid;
    int row = cl >> 3, cs = cl & 7;
    cgA[q] = cs ^ (row & 7);  // XOR-swizzle: pre-swizzled global source, linear LDS dest
    rowA[q] = row;
    int browG;
    if (MODE == 1) {
      int gate = (row >> 4) & 3;
      int hh = blockIdx.x * 32 + ((row >> 6) << 4) + (row & 15);
      browG = gate * 512 + hh;  // remap so wave nf-fragments = 4 gates at same h
    } else {
      browG = blockIdx.x * 128 + row;
    }
    browPtr[q] = (const char*)Bb + (size_t)browG * g.ldB * 2;
  }

  f32x4 acc[4][4];
#pragma unroll
  for (int a = 0; a < 4; ++a)
#pragma unroll
    for (int b = 0; b < 4; ++b) acc[a][b] = f32x4{0.f, 0.f, 0.f, 0.f};

  const int NSEG = (MODE == 1) ? 1 : ((MODE == 2) ? 2 : 3);
  for (int s = 0; s < NSEG; ++s) {
    const unsigned short* Ab = Aseg[s];
    if (MODE == 0 && Ab == 0) continue;  // zero segment (no left/up neighbor)
    const char* Abase = (const char*)Ab;
    const int kOffB = s * 1024;  // bytes: segment column offset in B
    for (int k0 = 0; k0 < 512; k0 += 64) {
#pragma unroll
      for (int q = 0; q < 4; ++q)
        gload16(Abase + ((size_t)(m0 + rowA[q]) * g.ldA + k0) * 2 + cgA[q] * 16,
                As + (q * 256 + tid) * 16);
#pragma unroll
      for (int q = 0; q < 4; ++q)
        gload16(browPtr[q] + kOffB + k0 * 2 + cgA[q] * 16,
                Bs + (q * 256 + tid) * 16);
      __syncthreads();
#pragma unroll
      for (int ks = 0; ks < 2; ++ks) {
        bfrag8 af[4], bfr[4];
#pragma unroll
        for (int mf = 0; mf < 4; ++mf) {
          int row = wr * 64 + mf * 16 + (lane & 15);
          af[mf] = *(const bfrag8*)(As + row * 128 +
                                    ((ks * 4 + (lane >> 4)) ^ (row & 7)) * 16);
        }
#pragma unroll
        for (int nf = 0; nf < 4; ++nf) {
          int row = wc * 64 + nf * 16 + (lane & 15);
          bfr[nf] = *(const bfrag8*)(Bs + row * 128 +
                                     ((ks * 4 + (lane >> 4)) ^ (row & 7)) * 16);
        }
#pragma unroll
        for (int mf = 0; mf < 4; ++mf)
#pragma unroll
          for (int nf = 0; nf < 4; ++nf)
            acc[mf][nf] = __builtin_amdgcn_mfma_f32_16x16x32_bf16(
                af[mf], bfr[nf], acc[mf][nf], 0, 0, 0);
      }
      __syncthreads();
    }
  }

  const int c4 = lane & 15;
  const int r4 = lane >> 4;

  if (MODE == 0) {
    const float* bias = (z == 0) ? g.biash : g.biasc;
    const int n0 = blockIdx.x * 128;
#pragma unroll
    for (int nf = 0; nf < 4; ++nf) {
      int colg = n0 + wc * 64 + nf * 16 + c4;
      float bv = bias[colg];
#pragma unroll
      for (int mf = 0; mf < 4; ++mf)
#pragma unroll
        for (int r = 0; r < 4; ++r) {
          int rowg = m0 + wr * 64 + mf * 16 + r4 * 4 + r;
          float v = acc[mf][nf][r] + bv;
          if (z == 0) g.outBf[(size_t)rowg * 512 + colg] = f2bf(v);
          else        g.outF[(size_t)rowg * 512 + colg] = v;
        }
    }
  } else if (MODE == 2) {
    const int n0 = blockIdx.x * 128;
#pragma unroll
    for (int nf = 0; nf < 4; ++nf) {
      int colg = n0 + wc * 64 + nf * 16 + c4;
      float bv = g.biash[colg];
#pragma unroll
      for (int mf = 0; mf < 4; ++mf)
#pragma unroll
        for (int r = 0; r < 4; ++r) {
          int rowg = m0 + wr * 64 + mf * 16 + r4 * 4 + r;
          float v = fmaxf(acc[mf][nf][r] + bv, 0.0f);
          g.outBf[(size_t)rowg * 256 + colg] = f2bf(v);
        }
    }
  } else {  // MODE 1: fused LSTM update
    int hcol = blockIdx.x * 32 + wc * 16 + c4;
    float wih[4], gb[4];
#pragma unroll
    for (int q = 0; q < 4; ++q) {
      wih[q] = g.W_ih[q * 512 + hcol];
      gb[q] = g.b_ih[q * 512 + hcol] + g.b_hh[q * 512 + hcol];
    }
#pragma unroll
    for (int mf = 0; mf < 4; ++mf)
#pragma unroll
      for (int r = 0; r < 4; ++r) {
        int b = m0 + wr * 64 + mf * 16 + r4 * 4 + r;
        float xi = g.x[b * 8 + g.cell];
        float vi = acc[mf][0][r] + xi * wih[0] + gb[0];
        float vf = acc[mf][1][r] + xi * wih[1] + gb[1];
        float vg = acc[mf][2][r] + xi * wih[2] + gb[2];
        float vo = acc[mf][3][r] + xi * wih[3] + gb[3];
        size_t offo = (size_t)b * 512 + hcol;
        float pcv = g.pc[offo];
        float cn = sigm(vf) * pcv + sigm(vi) * tanh_fast(vg);
        float hn = sigm(vo) * tanh_fast(cn);
        g.gh_out[offo] = hn;
        g.gc_out[offo] = cn;
        g.ring_h[offo] = f2bf(hn);
        g.ring_c[offo] = f2bf(cn);
        if (g.last) {
          float fh = hn + g.h_ext[offo];
          float fc = cn + g.c_ext[offo];
          g.fh_out[offo] = fh;
          g.fc_out[offo] = fc;
          g.finalBf[(size_t)b * 1024 + hcol] = f2bf(fh);
          g.finalBf[(size_t)b * 1024 + 512 + hcol] = f2bf(fc);
        }
      }
  }
}

__global__ __launch_bounds__(256)
void convert_pair(const float4* s0, uint2* d0, size_t n0,
                  const float4* s1, uint2* d1, size_t n1) {
  size_t total = n0 + n1;
  size_t stride = (size_t)gridDim.x * blockDim.x;
  for (size_t idx = (size_t)blockIdx.x * blockDim.x + threadIdx.x; idx < total;
       idx += stride) {
    const float4* s; uint2* d; size_t j;
    if (idx < n0) { s = s0; d = d0; j = idx; }
    else          { s = s1; d = d1; j = idx - n0; }
    float4 v = s[j];
    uint2 o;
    o.x = (uint32_t)f2bf(v.x) | ((uint32_t)f2bf(v.y) << 16);
    o.y = (uint32_t)f2bf(v.z) | ((uint32_t)f2bf(v.w) << 16);
    d[j] = o;
  }
}

__global__ __launch_bounds__(256)
void fc2_kernel(const unsigned short* hid, const float* W2, const float* b2,
                float* outlin) {
  int row = blockIdx.x * 4 + (threadIdx.x >> 6);
  int lane = threadIdx.x & 63;
  uint2 hv = ((const uint2*)(hid + (size_t)row * 256))[lane];
  float4 wv = ((const float4*)W2)[lane];
  float s = bf2f((unsigned short)(hv.x & 0xffffu)) * wv.x +
            bf2f((unsigned short)(hv.x >> 16)) * wv.y +
            bf2f((unsigned short)(hv.y & 0xffffu)) * wv.z +
            bf2f((unsigned short)(hv.y >> 16)) * wv.w;
#pragma unroll
  for (int o = 32; o > 0; o >>= 1) s += __shfl_down(s, o);
  if (lane == 0) outlin[row] = s + b2[0];
}

__global__ __launch_bounds__(1024)
void bn_kernel(const float* outlin, const float* gamma, const float* beta,
               float* out) {
  __shared__ float sred[16], sred2[16];
  __shared__ float smu, srs;
  float s = 0.f, s2 = 0.f;
  for (int i = threadIdx.x; i < 8192; i += 1024) {
    float v = outlin[i];
    s += v; s2 += v * v;
  }
#pragma unroll
  for (int o = 32; o > 0; o >>= 1) { s += __shfl_down(s, o); s2 += __shfl_down(s2, o); }
  if ((threadIdx.x & 63) == 0) { sred[threadIdx.x >> 6] = s; sred2[threadIdx.x >> 6] = s2; }
  __syncthreads();
  if (threadIdx.x == 0) {
    float S = 0.f, S2 = 0.f;
    for (int q = 0; q < 16; ++q) { S += sred[q]; S2 += sred2[q]; }
    float mu = S * (1.0f / 8192.0f);
    float var = S2 * (1.0f / 8192.0f) - mu * mu;
    smu = mu; srs = rsqrtf(var + 1e-5f);
  }
  __syncthreads();
  float gm = gamma[0], bt = beta[0];
  for (int i = threadIdx.x; i < 8192; i += 1024) {
    float v = (outlin[i] - smu) * srs * gm + bt;
    out[i] = sigm(v);
  }
}

extern "C" void kernel_launch(void* const* d_in, const int* in_sizes, int n_in,
                              void* d_out, int out_size, void* d_ws, size_t ws_size,
                              hipStream_t stream) {
  const float* x      = (const float*)d_in[0];
  const float* h_ext  = (const float*)d_in[1];
  const float* c_ext  = (const float*)d_in[2];
  const float* grid_h = (const float*)d_in[3];
  const float* grid_c = (const float*)d_in[4];
  const float* Wh     = (const float*)d_in[5];
  const float* bh     = (const float*)d_in[6];
  const float* Wc     = (const float*)d_in[7];
  const float* bc     = (const float*)d_in[8];
  const float* W_ih   = (const float*)d_in[9];
  const float* W_hh   = (const float*)d_in[10];
  const float* b_ih   = (const float*)d_in[11];
  const float* b_hh   = (const float*)d_in[12];
  const float* W1     = (const float*)d_in[13];
  const float* b1     = (const float*)d_in[14];
  const float* W2     = (const float*)d_in[15];
  const float* b2     = (const float*)d_in[16];
  const float* gamma  = (const float*)d_in[17];
  const float* beta   = (const float*)d_in[18];

  float* out = (float*)d_out;
  const size_t BH = (size_t)B_SZ * H_SZ;  // 4194304
  float* fh_out = out + 8192;
  float* fc_out = fh_out + BH;
  float* gh_out = fc_out + BH;
  float* gc_out = gh_out + 8 * BH;

  char* ws = (char*)d_ws;
  size_t off = 0;
  auto alloc = [&](size_t bytes) {
    char* p = ws + off;
    off = (off + bytes + 255) & ~(size_t)255;
    return p;
  };
  unsigned short* whB   = (unsigned short*)alloc(8ull * 512 * 1536 * 2);
  unsigned short* wcB   = (unsigned short*)alloc(8ull * 512 * 1536 * 2);
  unsigned short* whhB  = (unsigned short*)alloc(8ull * 2048 * 512 * 2);
  unsigned short* w1B   = (unsigned short*)alloc(256ull * 1024 * 2);
  unsigned short* hextB = (unsigned short*)alloc(BH * 2);
  unsigned short* cextB = (unsigned short*)alloc(BH * 2);
  unsigned short* ringH[3]; unsigned short* ringC[3];
  for (int s = 0; s < 3; ++s) {
    ringH[s] = (unsigned short*)alloc(BH * 2);
    ringC[s] = (unsigned short*)alloc(BH * 2);
  }
  unsigned short* phB    = (unsigned short*)alloc(BH * 2);
  float*          pcF    = (float*)alloc(BH * 4);
  unsigned short* finalB = (unsigned short*)alloc((size_t)B_SZ * 1024 * 2);
  unsigned short* hidB   = (unsigned short*)alloc((size_t)B_SZ * 256 * 2);
  float*          outlin = (float*)alloc((size_t)B_SZ * 4);

  // one-time f32 -> bf16 conversion of weights + ext states
  convert_pair<<<2048, 256, 0, stream>>>((const float4*)Wh, (uint2*)whB, 8ull * 512 * 1536 / 4,
                                         (const float4*)Wc, (uint2*)wcB, 8ull * 512 * 1536 / 4);
  convert_pair<<<2048, 256, 0, stream>>>((const float4*)W_hh, (uint2*)whhB, 8ull * 2048 * 512 / 4,
                                         (const float4*)W1, (uint2*)w1B, 256ull * 1024 / 4);
  convert_pair<<<2048, 256, 0, stream>>>((const float4*)h_ext, (uint2*)hextB, BH / 4,
                                         (const float4*)c_ext, (uint2*)cextB, BH / 4);

  for (int cell = 0; cell < 8; ++cell) {
    int i = cell >> 1, j = cell & 1;
    int slot = cell % 3;
    // bf16 copy of this cell's prev state (ring slot reused for new state after)
    convert_pair<<<2048, 256, 0, stream>>>(
        (const float4*)(grid_h + cell * BH), (uint2*)ringH[slot], BH / 4,
        (const float4*)(grid_c + cell * BH), (uint2*)ringC[slot], BH / 4);

    GemmArgs a = {};
    const unsigned short *hl, *cl_, *hu, *cu;
    if (cell == 0)      { hl = hextB;              cl_ = cextB; }
    else if (j > 0)     { hl = ringH[(cell - 1) % 3]; cl_ = ringC[(cell - 1) % 3]; }
    else                { hl = 0;                  cl_ = 0; }
    if (i > 0)          { hu = ringH[(cell - 2) % 3]; cu = ringC[(cell - 2) % 3]; }
    else                { hu = 0;                  cu = 0; }
    a.Ah[0] = hl; a.Ah[1] = hu; a.Ah[2] = ringH[slot];
    a.Ac[0] = cl_; a.Ac[1] = cu; a.Ac[2] = ringC[slot];
    a.Bh = whB + (size_t)cell * 512 * 1536;
    a.Bc = wcB + (size_t)cell * 512 * 1536;
    a.ldA = 512; a.ldB = 1536;
    a.biash = bh + cell * 512; a.biasc = bc + cell * 512;
    a.outBf = phB; a.outF = pcF;
    gemm_k<0><<<dim3(4, 64, 2), 256, 0, stream>>>(a);

    GemmArgs ga = {};
    ga.Ah[0] = phB; ga.ldA = 512;
    ga.Bh = whhB + (size_t)cell * 2048 * 512; ga.ldB = 512;
    ga.pc = pcF; ga.x = x;
    ga.W_ih = W_ih + cell * 2048;
    ga.b_ih = b_ih + cell * 2048;
    ga.b_hh = b_hh + cell * 2048;
    ga.cell = cell; ga.last = (cell == 7);
    ga.gh_out = gh_out + cell * BH; ga.gc_out = gc_out + cell * BH;
    ga.ring_h = ringH[slot]; ga.ring_c = ringC[slot];
    ga.h_ext = h_ext; ga.c_ext = c_ext;
    ga.fh_out = fh_out; ga.fc_out = fc_out; ga.finalBf = finalB;
    gemm_k<1><<<dim3(16, 64, 1), 256, 0, stream>>>(ga);
  }

  GemmArgs gf = {};
  gf.Ah[0] = finalB; gf.Ah[1] = finalB + 512; gf.ldA = 1024;
  gf.Bh = w1B; gf.ldB = 1024;
  gf.biash = b1;
  gf.outBf = hidB;
  gemm_k<2><<<dim3(2, 64, 1), 256, 0, stream>>>(gf);

  fc2_kernel<<<2048, 256, 0, stream>>>(hidB, W2, b2, outlin);
  bn_kernel<<<1, 1024, 0, stream>>>(outlin, gamma, beta, out);
}